// Round 3
// baseline (478.200 us; speedup 1.0000x reference)
//
#include <hip/hip_runtime.h>

#define B_  2048
#define N_  64
#define H_  4
#define FI  256
#define FO  256
#define HF  1024   // H*FO

typedef _Float16 f16;
typedef _Float16 f16x8 __attribute__((ext_vector_type(8)));
typedef _Float16 f16x4 __attribute__((ext_vector_type(4)));
typedef float f32x4 __attribute__((ext_vector_type(4)));

#define MFMA16(a,b,c) __builtin_amdgcn_mfma_f32_16x16x32_f16(a, b, c, 0, 0, 0)

// ---------------------------------------------------------------------------
// W prep: W [256][1024] f32 -> f16 MFMA B-fragments in workspace.
// layout: frag[kt(8)][ctg(64)][lane(64)][j(8)]
// element: W[kt*32 + (lane>>4)*8 + j][ctg*16 + (lane&15)]
// ---------------------------------------------------------------------------
__global__ __launch_bounds__(256) void prep_w_kernel(const float* __restrict__ W,
                                                     f16* __restrict__ wfrag) {
    int tid  = blockIdx.x * 256 + threadIdx.x;   // 0..32767
    int lane = tid & 63;
    int ctg  = (tid >> 6) & 63;
    int kt   = tid >> 12;                        // 0..7
    int krow = kt * 32 + (lane >> 4) * 8;
    int col  = ctg * 16 + (lane & 15);
    f16x8 v;
#pragma unroll
    for (int j = 0; j < 8; ++j)
        v[j] = (f16)W[(size_t)(krow + j) * HF + col];
    *((f16x8*)wfrag + tid) = v;
}

// ---------------------------------------------------------------------------
// Fused GAT kernel: 1 block = 1 batch, 8 waves, heads processed SEQUENTIALLY.
// Per head w: GEMM1 cols split across 8 waves (32 cols each);
//             softmax/GEMM2: wave wv -> row-tile rt=wv>>1, col-half ch=wv&1
//             (softmax duplicated between the two ch waves of a row-tile).
// LDS (78336 B total -> 2 blocks/CU):
//   [0, 32768)      sA    input f16 [64 row][256 k], XOR-swizzled
//   [32768, 65536)  sHT   h^T f16 [256 col][64 node] for CURRENT head, swizzled
//   [65536, 73728)  sAdjH adj f16 permuted [64 i][4 g][16 qq], swizzled
//   [73728, 75776)  sCi   per-wave coeff_i partials [8][64] f32
//   [75776, 77824)  sCj   per-wave coeff_j partials [8][64] f32
//   [77824, 78080)  sCiS  summed coeff_i [64] f32
//   [78080, 78336)  sCjS  summed coeff_j [64] f32
// ---------------------------------------------------------------------------
#define SMEM_BYTES 78336
#define SHT_OFF    32768
#define SADJ_OFF   65536
#define SCI_OFF    73728
#define SCJ_OFF    75776
#define SCIS_OFF   77824
#define SCJS_OFF   78080

__global__ __launch_bounds__(512, 4) void gat_kernel(
    const float* __restrict__ input, const float* __restrict__ adj,
    const f16* __restrict__ wfrag, const float* __restrict__ a_i,
    const float* __restrict__ a_j, const float* __restrict__ bias,
    float* __restrict__ out)
{
    __shared__ unsigned char smem[SMEM_BYTES] __attribute__((aligned(16)));
    float* sCi  = (float*)(smem + SCI_OFF);
    float* sCj  = (float*)(smem + SCJ_OFF);
    float* sCiS = (float*)(smem + SCIS_OFF);
    float* sCjS = (float*)(smem + SCJS_OFF);

    const int b    = blockIdx.x;
    const int tid  = threadIdx.x;
    const int wv   = tid >> 6;      // wave 0..7
    const int lane = tid & 63;
    const int g    = lane >> 4;
    const int c15  = lane & 15;
    const int rt2  = wv >> 1;       // row-tile for softmax/GEMM2
    const int ch   = wv & 1;        // col-half for GEMM2

    // ---- phase 0: stage input (f32->f16, swizzled) ----
    {
        const float* inb = input + (size_t)b * (N_ * FI);
#pragma unroll
        for (int c = 0; c < 4; ++c) {
            int idx = tid + 512 * c;          // 0..2047 8-float chunks
            int row = idx >> 5;
            int k0  = (idx & 31) << 3;
            const float4* p = (const float4*)(inb + row * FI + k0);
            float4 v0 = p[0], v1 = p[1];
            f16x8 h8;
            h8[0] = (f16)v0.x; h8[1] = (f16)v0.y; h8[2] = (f16)v0.z; h8[3] = (f16)v0.w;
            h8[4] = (f16)v1.x; h8[5] = (f16)v1.y; h8[6] = (f16)v1.z; h8[7] = (f16)v1.w;
            unsigned addr = (unsigned)(row * 512 + k0 * 2) ^ ((unsigned)(row & 7) << 4);
            *(f16x8*)(smem + addr) = h8;
        }
        // ---- stage adj: f32 -> f16, permuted [i][g][qq] so softmax reads b128 ----
        {
            int i  = tid >> 3;
            int j0 = (tid & 7) << 3;          // multiple of 8
            const float4* p = (const float4*)(adj + (size_t)b * (N_ * N_) + i * N_ + j0);
            float4 v0 = p[0], v1 = p[1];
            f16x8 a8;
            a8[0] = (f16)v0.x; a8[1] = (f16)v0.y; a8[2] = (f16)v0.z; a8[3] = (f16)v0.w;
            a8[4] = (f16)v1.x; a8[5] = (f16)v1.y; a8[6] = (f16)v1.z; a8[7] = (f16)v1.w;
            int gg = (j0 >> 3) & 3;
            int kt = j0 >> 5;
            unsigned addr = SADJ_OFF + ((unsigned)(i * 128 + gg * 32 + kt * 16)
                                        ^ ((unsigned)(i & 7) << 4));
            *(f16x8*)(smem + addr) = a8;
        }
    }
    __syncthreads();

#pragma unroll 1
    for (int w = 0; w < H_; ++w) {
        // ---- GEMM1 compute: this wave's 32 cols of head w (reads sA + wfrag) ----
        f32x4 acc[4][2];
#pragma unroll
        for (int rt = 0; rt < 4; ++rt)
#pragma unroll
            for (int ct = 0; ct < 2; ++ct) {
                f32x4 z = {0.f, 0.f, 0.f, 0.f};
                acc[rt][ct] = z;
            }
#pragma unroll
        for (int kt = 0; kt < 8; ++kt) {
            f16x8 aF[4];
#pragma unroll
            for (int rt = 0; rt < 4; ++rt) {
                int row = rt * 16 + c15;
                unsigned addr = ((unsigned)(row * 512 + (kt * 32 + g * 8) * 2))
                                ^ ((unsigned)(row & 7) << 4);
                aF[rt] = *(const f16x8*)(smem + addr);
            }
            f16x8 bF[2];
#pragma unroll
            for (int ct = 0; ct < 2; ++ct) {
                int ctg = w * 16 + wv * 2 + ct;
                bF[ct] = *((const f16x8*)wfrag + ((kt * 64 + ctg) * 64 + lane));
            }
#pragma unroll
            for (int rt = 0; rt < 4; ++rt)
#pragma unroll
                for (int ct = 0; ct < 2; ++ct)
                    acc[rt][ct] = MFMA16(aF[rt], bF[ct], acc[rt][ct]);
        }

        __syncthreads();   // all waves done reading sHT (prev head's GEMM2)

        // ---- epilogue: h^T -> sHT (swizzled) + coeff partials ----
        float ciP[16], cjP[16];
#pragma unroll
        for (int q = 0; q < 16; ++q) { ciP[q] = 0.f; cjP[q] = 0.f; }
#pragma unroll
        for (int ct = 0; ct < 2; ++ct) {
            int col = wv * 32 + ct * 16 + c15;      // 0..255
            float aIc = a_i[w * FO + col];
            float aJc = a_j[w * FO + col];
#pragma unroll
            for (int rt = 0; rt < 4; ++rt) {
                f16x4 h4;
#pragma unroll
                for (int r = 0; r < 4; ++r) {
                    float v = acc[rt][ct][r];
                    ciP[rt * 4 + r] += v * aIc;
                    cjP[rt * 4 + r] += v * aJc;
                    h4[r] = (f16)v;
                }
                unsigned addr = SHT_OFF + (((unsigned)(col * 128 + (rt * 16 + g * 4) * 2))
                                           ^ ((unsigned)(col & 7) << 4));
                *(f16x4*)(smem + addr) = h4;
            }
        }
        // reduce coeff partials across the 16 lanes of each g-group
#pragma unroll
        for (int s = 1; s < 16; s <<= 1) {
#pragma unroll
            for (int q = 0; q < 16; ++q) {
                ciP[q] += __shfl_xor(ciP[q], s);
                cjP[q] += __shfl_xor(cjP[q], s);
            }
        }
        if (c15 == 0) {
#pragma unroll
            for (int q = 0; q < 16; ++q) {
                int node = (q >> 2) * 16 + g * 4 + (q & 3);
                sCi[wv * 64 + node] = ciP[q];
                sCj[wv * 64 + node] = cjP[q];
            }
        }
        __syncthreads();

        // ---- cross-wave coeff sum ----
        if (tid < 64) {
            float s = 0.f;
#pragma unroll
            for (int v = 0; v < 8; ++v) s += sCi[v * 64 + tid];
            sCiS[tid] = s;
        } else if (tid < 128) {
            int t = tid - 64;
            float s = 0.f;
#pragma unroll
            for (int v = 0; v < 8; ++v) s += sCj[v * 64 + t];
            sCjS[t] = s;
        }
        __syncthreads();

        // ---- softmax for rows rt2*16..+16 (dup'd across the 2 ch-waves) ----
        f16x8 attnF[2];
        {
            int i = rt2 * 16 + c15;
            float ci = sCiS[i];
            f16x8 adjv[2];
#pragma unroll
            for (int kt = 0; kt < 2; ++kt) {
                unsigned addr = SADJ_OFF + ((unsigned)(i * 128 + g * 32 + kt * 16)
                                            ^ ((unsigned)(i & 7) << 4));
                adjv[kt] = *(const f16x8*)(smem + addr);
            }
            float sv[16];
            float m = -1e30f;
#pragma unroll
            for (int q = 0; q < 16; ++q) {
                int kt = q >> 3, jj = q & 7;
                int j = kt * 32 + g * 8 + jj;
                float av = (float)adjv[kt][jj];
                float e = ci + sCjS[j];
                e = fmaxf(e, 0.2f * e);          // leaky_relu slope 0.2
                float s = e * av;
                sv[q] = s;
                m = fmaxf(m, s);
            }
            m = fmaxf(m, __shfl_xor(m, 16));
            m = fmaxf(m, __shfl_xor(m, 32));
            float sum = 0.f;
#pragma unroll
            for (int q = 0; q < 16; ++q) { float p = __expf(sv[q] - m); sv[q] = p; sum += p; }
            sum += __shfl_xor(sum, 16);
            sum += __shfl_xor(sum, 32);
            float rs = 1.0f / sum;
#pragma unroll
            for (int q = 0; q < 16; ++q) {
                int kt = q >> 3, jj = q & 7;
                attnF[kt][jj] = (f16)(sv[q] * rs * (float)adjv[kt][jj]);
            }
        }

        // ---- GEMM2: rows rt2*16..+16, cols ch*128..+128 of head w ----
        f32x4 acc2[8];
#pragma unroll
        for (int ct = 0; ct < 8; ++ct) {
            f32x4 z = {0.f, 0.f, 0.f, 0.f};
            acc2[ct] = z;
        }
#pragma unroll
        for (int kt = 0; kt < 2; ++kt) {
#pragma unroll
            for (int ct = 0; ct < 8; ++ct) {
                int col = ch * 128 + ct * 16 + c15;
                unsigned addr = SHT_OFF + (((unsigned)(col * 128 + (kt * 32 + g * 8) * 2))
                                           ^ ((unsigned)(col & 7) << 4));
                f16x8 bF = *(const f16x8*)(smem + addr);
                acc2[ct] = MFMA16(attnF[kt], bF, acc2[ct]);
            }
        }
#pragma unroll
        for (int ct = 0; ct < 8; ++ct) {
            int colg = w * FO + ch * 128 + ct * 16 + c15;
            float bv = bias[colg];
#pragma unroll
            for (int r = 0; r < 4; ++r) {
                int row = rt2 * 16 + g * 4 + r;
                out[((size_t)b * N_ + row) * HF + colg] = acc2[ct][r] + bv;
            }
        }
    }
}

extern "C" void kernel_launch(void* const* d_in, const int* in_sizes, int n_in,
                              void* d_out, int out_size, void* d_ws, size_t ws_size,
                              hipStream_t stream) {
    const float* input = (const float*)d_in[0];
    const float* adj   = (const float*)d_in[1];
    const float* W     = (const float*)d_in[2];
    const float* a_i   = (const float*)d_in[3];
    const float* a_j   = (const float*)d_in[4];
    const float* bias  = (const float*)d_in[5];
    float* outp  = (float*)d_out;
    f16*   wfrag = (f16*)d_ws;   // 512 KB

    prep_w_kernel<<<128, 256, 0, stream>>>(W, wfrag);
    gat_kernel<<<B_, 512, 0, stream>>>(input, adj, wfrag, a_i, a_j, bias, outp);
}

// Round 4
// 362.102 us; speedup vs baseline: 1.3206x; 1.3206x over previous
//
#include <hip/hip_runtime.h>

#define B_  2048
#define N_  64
#define H_  4
#define FI  256
#define FO  256
#define HF  1024   // H*F_OUT

typedef _Float16 f16;
typedef _Float16 f16x8 __attribute__((ext_vector_type(8)));
typedef _Float16 f16x4 __attribute__((ext_vector_type(4)));
typedef float f32x4 __attribute__((ext_vector_type(4)));

#define MFMA16(a,b,c) __builtin_amdgcn_mfma_f32_16x16x32_f16(a, b, c, 0, 0, 0)

// ---------------------------------------------------------------------------
// W prep: W [256][1024] f32 -> f16 MFMA B-fragments in workspace.
// layout: frag[kt(8)][ctg(64)][lane(64)][j(8)]
// element: W[kt*32 + (lane>>4)*8 + j][ctg*16 + (lane&15)]
// ---------------------------------------------------------------------------
__global__ __launch_bounds__(256) void prep_w_kernel(const float* __restrict__ W,
                                                     f16* __restrict__ wfrag) {
    int tid  = blockIdx.x * 256 + threadIdx.x;   // 0..32767
    int lane = tid & 63;
    int ctg  = (tid >> 6) & 63;
    int kt   = tid >> 12;                        // 0..7
    int krow = kt * 32 + (lane >> 4) * 8;
    int col  = ctg * 16 + (lane & 15);
    f16x8 v;
#pragma unroll
    for (int j = 0; j < 8; ++j)
        v[j] = (f16)W[(size_t)(krow + j) * HF + col];
    *((f16x8*)wfrag + tid) = v;
}

// ---------------------------------------------------------------------------
// Fused GAT kernel: 1 block = 1 batch, 8 waves, heads processed SEQUENTIALLY.
// Per head w: GEMM1 cols split across 8 waves (32 cols each);
//             softmax/GEMM2: wave wv -> row-tile rt=wv>>1, col-half ch=wv&1
//             (softmax duplicated between the two ch waves of a row-tile).
// LDS (78336 B total -> 2 blocks/CU):
//   [0, 32768)      sA    input f16 [64 row][256 k], XOR-swizzled
//   [32768, 65536)  sHT   h^T f16 [256 col][64 node] for CURRENT head, swizzled
//   [65536, 73728)  sAdjH adj f16 permuted [64 i][4 g][16 qq], swizzled
//   [73728, 75776)  sCi   per-wave coeff_i partials [8][64] f32
//   [75776, 77824)  sCj   per-wave coeff_j partials [8][64] f32
//   [77824, 78080)  sCiS  summed coeff_i [64] f32
//   [78080, 78336)  sCjS  summed coeff_j [64] f32
// __launch_bounds__(512, 2): arg2 = min BLOCKS/CU on this toolchain (r3
// evidence: arg2=4 -> VGPR 64 = 8 waves/SIMD cap). 2 blocks/CU -> cap 128.
// ---------------------------------------------------------------------------
#define SMEM_BYTES 78336
#define SHT_OFF    32768
#define SADJ_OFF   65536
#define SCI_OFF    73728
#define SCJ_OFF    75776
#define SCIS_OFF   77824
#define SCJS_OFF   78080

__global__ __launch_bounds__(512, 2) void gat_kernel(
    const float* __restrict__ input, const float* __restrict__ adj,
    const f16* __restrict__ wfrag, const float* __restrict__ a_i,
    const float* __restrict__ a_j, const float* __restrict__ bias,
    float* __restrict__ out)
{
    __shared__ unsigned char smem[SMEM_BYTES] __attribute__((aligned(16)));
    float* sCi  = (float*)(smem + SCI_OFF);
    float* sCj  = (float*)(smem + SCJ_OFF);
    float* sCiS = (float*)(smem + SCIS_OFF);
    float* sCjS = (float*)(smem + SCJS_OFF);

    const int b    = blockIdx.x;
    const int tid  = threadIdx.x;
    const int wv   = tid >> 6;      // wave 0..7
    const int lane = tid & 63;
    const int g    = lane >> 4;
    const int c15  = lane & 15;
    const int rt2  = wv >> 1;       // row-tile for softmax/GEMM2
    const int ch   = wv & 1;        // col-half for GEMM2

    // ---- phase 0: stage input (f32->f16, swizzled) ----
    {
        const float* inb = input + (size_t)b * (N_ * FI);
#pragma unroll
        for (int c = 0; c < 4; ++c) {
            int idx = tid + 512 * c;          // 0..2047 8-float chunks
            int row = idx >> 5;
            int k0  = (idx & 31) << 3;
            const float4* p = (const float4*)(inb + row * FI + k0);
            float4 v0 = p[0], v1 = p[1];
            f16x8 h8;
            h8[0] = (f16)v0.x; h8[1] = (f16)v0.y; h8[2] = (f16)v0.z; h8[3] = (f16)v0.w;
            h8[4] = (f16)v1.x; h8[5] = (f16)v1.y; h8[6] = (f16)v1.z; h8[7] = (f16)v1.w;
            unsigned addr = (unsigned)(row * 512 + k0 * 2) ^ ((unsigned)(row & 7) << 4);
            *(f16x8*)(smem + addr) = h8;
        }
        // ---- stage adj: f32 -> f16, permuted [i][g][qq] so softmax reads b128 ----
        {
            int i  = tid >> 3;
            int j0 = (tid & 7) << 3;          // multiple of 8
            const float4* p = (const float4*)(adj + (size_t)b * (N_ * N_) + i * N_ + j0);
            float4 v0 = p[0], v1 = p[1];
            f16x8 a8;
            a8[0] = (f16)v0.x; a8[1] = (f16)v0.y; a8[2] = (f16)v0.z; a8[3] = (f16)v0.w;
            a8[4] = (f16)v1.x; a8[5] = (f16)v1.y; a8[6] = (f16)v1.z; a8[7] = (f16)v1.w;
            int gg = (j0 >> 3) & 3;
            int kt = j0 >> 5;
            unsigned addr = SADJ_OFF + ((unsigned)(i * 128 + gg * 32 + kt * 16)
                                        ^ ((unsigned)(i & 7) << 4));
            *(f16x8*)(smem + addr) = a8;
        }
    }
    __syncthreads();

#pragma unroll 1
    for (int w = 0; w < H_; ++w) {
        // ---- GEMM1 compute: this wave's 32 cols of head w (reads sA + wfrag) ----
        f32x4 acc[4][2];
#pragma unroll
        for (int rt = 0; rt < 4; ++rt)
#pragma unroll
            for (int ct = 0; ct < 2; ++ct) {
                f32x4 z = {0.f, 0.f, 0.f, 0.f};
                acc[rt][ct] = z;
            }
#pragma unroll
        for (int kt = 0; kt < 8; ++kt) {
            f16x8 aF[4];
#pragma unroll
            for (int rt = 0; rt < 4; ++rt) {
                int row = rt * 16 + c15;
                unsigned addr = ((unsigned)(row * 512 + (kt * 32 + g * 8) * 2))
                                ^ ((unsigned)(row & 7) << 4);
                aF[rt] = *(const f16x8*)(smem + addr);
            }
            f16x8 bF[2];
#pragma unroll
            for (int ct = 0; ct < 2; ++ct) {
                int ctg = w * 16 + wv * 2 + ct;
                bF[ct] = *((const f16x8*)wfrag + ((kt * 64 + ctg) * 64 + lane));
            }
#pragma unroll
            for (int rt = 0; rt < 4; ++rt)
#pragma unroll
                for (int ct = 0; ct < 2; ++ct)
                    acc[rt][ct] = MFMA16(aF[rt], bF[ct], acc[rt][ct]);
        }

        __syncthreads();   // all waves done reading sHT (prev head's GEMM2)

        // ---- epilogue: h^T -> sHT (swizzled) + coeff partials ----
        float ciP[16], cjP[16];
#pragma unroll
        for (int q = 0; q < 16; ++q) { ciP[q] = 0.f; cjP[q] = 0.f; }
#pragma unroll
        for (int ct = 0; ct < 2; ++ct) {
            int col = wv * 32 + ct * 16 + c15;      // 0..255
            float aIc = a_i[w * FO + col];
            float aJc = a_j[w * FO + col];
#pragma unroll
            for (int rt = 0; rt < 4; ++rt) {
                f16x4 h4;
#pragma unroll
                for (int r = 0; r < 4; ++r) {
                    float v = acc[rt][ct][r];
                    ciP[rt * 4 + r] += v * aIc;
                    cjP[rt * 4 + r] += v * aJc;
                    h4[r] = (f16)v;
                }
                unsigned addr = SHT_OFF + (((unsigned)(col * 128 + (rt * 16 + g * 4) * 2))
                                           ^ ((unsigned)(col & 7) << 4));
                *(f16x4*)(smem + addr) = h4;
            }
        }
        // reduce coeff partials across the 16 lanes of each g-group
#pragma unroll
        for (int s = 1; s < 16; s <<= 1) {
#pragma unroll
            for (int q = 0; q < 16; ++q) {
                ciP[q] += __shfl_xor(ciP[q], s);
                cjP[q] += __shfl_xor(cjP[q], s);
            }
        }
        if (c15 == 0) {
#pragma unroll
            for (int q = 0; q < 16; ++q) {
                int node = (q >> 2) * 16 + g * 4 + (q & 3);
                sCi[wv * 64 + node] = ciP[q];
                sCj[wv * 64 + node] = cjP[q];
            }
        }
        __syncthreads();

        // ---- cross-wave coeff sum ----
        if (tid < 64) {
            float s = 0.f;
#pragma unroll
            for (int v = 0; v < 8; ++v) s += sCi[v * 64 + tid];
            sCiS[tid] = s;
        } else if (tid < 128) {
            int t = tid - 64;
            float s = 0.f;
#pragma unroll
            for (int v = 0; v < 8; ++v) s += sCj[v * 64 + t];
            sCjS[t] = s;
        }
        __syncthreads();

        // ---- softmax for rows rt2*16..+16 (dup'd across the 2 ch-waves) ----
        f16x8 attnF[2];
        {
            int i = rt2 * 16 + c15;
            float ci = sCiS[i];
            f16x8 adjv[2];
#pragma unroll
            for (int kt = 0; kt < 2; ++kt) {
                unsigned addr = SADJ_OFF + ((unsigned)(i * 128 + g * 32 + kt * 16)
                                            ^ ((unsigned)(i & 7) << 4));
                adjv[kt] = *(const f16x8*)(smem + addr);
            }
            float sv[16];
            float m = -1e30f;
#pragma unroll
            for (int q = 0; q < 16; ++q) {
                int kt = q >> 3, jj = q & 7;
                int j = kt * 32 + g * 8 + jj;
                float av = (float)adjv[kt][jj];
                float e = ci + sCjS[j];
                e = fmaxf(e, 0.2f * e);          // leaky_relu slope 0.2
                float s = e * av;
                sv[q] = s;
                m = fmaxf(m, s);
            }
            m = fmaxf(m, __shfl_xor(m, 16));
            m = fmaxf(m, __shfl_xor(m, 32));
            float sum = 0.f;
#pragma unroll
            for (int q = 0; q < 16; ++q) { float p = __expf(sv[q] - m); sv[q] = p; sum += p; }
            sum += __shfl_xor(sum, 16);
            sum += __shfl_xor(sum, 32);
            float rs = 1.0f / sum;
#pragma unroll
            for (int q = 0; q < 16; ++q) {
                int kt = q >> 3, jj = q & 7;
                attnF[kt][jj] = (f16)(sv[q] * rs * (float)adjv[kt][jj]);
            }
        }

        // ---- GEMM2: rows rt2*16..+16, cols ch*128..+128 of head w ----
        f32x4 acc2[8];
#pragma unroll
        for (int ct = 0; ct < 8; ++ct) {
            f32x4 z = {0.f, 0.f, 0.f, 0.f};
            acc2[ct] = z;
        }
#pragma unroll
        for (int kt = 0; kt < 2; ++kt) {
#pragma unroll
            for (int ct = 0; ct < 8; ++ct) {
                int col = ch * 128 + ct * 16 + c15;
                unsigned addr = SHT_OFF + (((unsigned)(col * 128 + (kt * 32 + g * 8) * 2))
                                           ^ ((unsigned)(col & 7) << 4));
                f16x8 bF = *(const f16x8*)(smem + addr);
                acc2[ct] = MFMA16(attnF[kt], bF, acc2[ct]);
            }
        }
#pragma unroll
        for (int ct = 0; ct < 8; ++ct) {
            int colg = w * FO + ch * 128 + ct * 16 + c15;
            float bv = bias[colg];
#pragma unroll
            for (int r = 0; r < 4; ++r) {
                int row = rt2 * 16 + g * 4 + r;
                out[((size_t)b * N_ + row) * HF + colg] = acc2[ct][r] + bv;
            }
        }
    }
}

extern "C" void kernel_launch(void* const* d_in, const int* in_sizes, int n_in,
                              void* d_out, int out_size, void* d_ws, size_t ws_size,
                              hipStream_t stream) {
    const float* input = (const float*)d_in[0];
    const float* adj   = (const float*)d_in[1];
    const float* W     = (const float*)d_in[2];
    const float* a_i   = (const float*)d_in[3];
    const float* a_j   = (const float*)d_in[4];
    const float* bias  = (const float*)d_in[5];
    float* outp  = (float*)d_out;
    f16*   wfrag = (f16*)d_ws;   // 512 KB

    prep_w_kernel<<<128, 256, 0, stream>>>(W, wfrag);
    gat_kernel<<<B_, 512, 0, stream>>>(input, adj, wfrag, a_i, a_j, bias, outp);
}

// Round 5
// 346.978 us; speedup vs baseline: 1.3782x; 1.0436x over previous
//
#include <hip/hip_runtime.h>

#define B_  2048
#define N_  64
#define H_  4
#define FI  256
#define FO  256
#define HF  1024   // H*F_OUT

typedef _Float16 f16;
typedef _Float16 f16x8 __attribute__((ext_vector_type(8)));
typedef _Float16 f16x4 __attribute__((ext_vector_type(4)));
typedef float f32x4 __attribute__((ext_vector_type(4)));

#define MFMA16(a,b,c) __builtin_amdgcn_mfma_f32_16x16x32_f16(a, b, c, 0, 0, 0)

// ---------------------------------------------------------------------------
// W prep: W [256][1024] f32 -> f16 MFMA B-fragments in workspace.
// layout: frag[kt(8)][ctg(64)][lane(64)][j(8)]
// element: W[kt*32 + (lane>>4)*8 + j][ctg*16 + (lane&15)]
// ---------------------------------------------------------------------------
__global__ __launch_bounds__(256) void prep_w_kernel(const float* __restrict__ W,
                                                     f16* __restrict__ wfrag) {
    int tid  = blockIdx.x * 256 + threadIdx.x;   // 0..32767
    int lane = tid & 63;
    int ctg  = (tid >> 6) & 63;
    int kt   = tid >> 12;                        // 0..7
    int krow = kt * 32 + (lane >> 4) * 8;
    int col  = ctg * 16 + (lane & 15);
    f16x8 v;
#pragma unroll
    for (int j = 0; j < 8; ++j)
        v[j] = (f16)W[(size_t)(krow + j) * HF + col];
    *((f16x8*)wfrag + tid) = v;
}

// ---------------------------------------------------------------------------
// Fused GAT kernel: 1 block = 1 batch, 8 waves, heads processed SEQUENTIALLY.
// Per head w: GEMM1 cols split across 8 waves (32 cols each);
//             softmax/GEMM2: wave wv -> row-tile rt=wv>>1, col-half ch=wv&1
//             (softmax duplicated between the two ch waves of a row-tile;
//              adj rows for the wave's row-tile live in 16 REGISTERS, loaded
//              once from global — adj is NOT staged in LDS).
// LDS (70144 B total -> 2 blocks/CU; r4's 78336 appeared to exceed the
// runtime's per-CU LDS co-residency limit, leaving 1 block/CU):
//   [0, 32768)      sA    input f16 [64 row][256 k], XOR-swizzled
//   [32768, 65536)  sHT   h^T f16 [256 col][64 node] for CURRENT head, swizzled
//   [65536, 67584)  sCi   per-wave coeff_i partials [8][64] f32
//   [67584, 69632)  sCj   per-wave coeff_j partials [8][64] f32
//   [69632, 69888)  sCiS  summed coeff_i [64] f32
//   [69888, 70144)  sCjS  summed coeff_j [64] f32
// __launch_bounds__(512, 2): arg2 = min BLOCKS/CU on this toolchain (r3/r4
// evidence) -> VGPR cap 128.
// ---------------------------------------------------------------------------
#define SMEM_BYTES 70144
#define SHT_OFF    32768
#define SCI_OFF    65536
#define SCJ_OFF    67584
#define SCIS_OFF   69632
#define SCJS_OFF   69888

__global__ __launch_bounds__(512, 2) void gat_kernel(
    const float* __restrict__ input, const float* __restrict__ adj,
    const f16* __restrict__ wfrag, const float* __restrict__ a_i,
    const float* __restrict__ a_j, const float* __restrict__ bias,
    float* __restrict__ out)
{
    __shared__ unsigned char smem[SMEM_BYTES] __attribute__((aligned(16)));
    float* sCi  = (float*)(smem + SCI_OFF);
    float* sCj  = (float*)(smem + SCJ_OFF);
    float* sCiS = (float*)(smem + SCIS_OFF);
    float* sCjS = (float*)(smem + SCJS_OFF);

    const int b    = blockIdx.x;
    const int tid  = threadIdx.x;
    const int wv   = tid >> 6;      // wave 0..7
    const int lane = tid & 63;
    const int g    = lane >> 4;
    const int c15  = lane & 15;
    const int rt2  = wv >> 1;       // row-tile for softmax/GEMM2
    const int ch   = wv & 1;        // col-half for GEMM2

    // ---- adj rows for this wave's softmax row-tile -> 16 registers ----
    // lane (g,c15): row i = rt2*16+c15, j = kt*32 + g*8 + jj (kt=q>>3, jj=q&7)
    float av[16];
    {
        const float* adjb = adj + (size_t)b * (N_ * N_) + (rt2 * 16 + c15) * N_ + g * 8;
        float4 p0 = *(const float4*)(adjb);
        float4 p1 = *(const float4*)(adjb + 4);
        float4 p2 = *(const float4*)(adjb + 32);
        float4 p3 = *(const float4*)(adjb + 36);
        av[0]  = p0.x; av[1]  = p0.y; av[2]  = p0.z; av[3]  = p0.w;
        av[4]  = p1.x; av[5]  = p1.y; av[6]  = p1.z; av[7]  = p1.w;
        av[8]  = p2.x; av[9]  = p2.y; av[10] = p2.z; av[11] = p2.w;
        av[12] = p3.x; av[13] = p3.y; av[14] = p3.z; av[15] = p3.w;
    }

    // ---- phase 0: stage input (f32->f16, swizzled) ----
    {
        const float* inb = input + (size_t)b * (N_ * FI);
#pragma unroll
        for (int c = 0; c < 4; ++c) {
            int idx = tid + 512 * c;          // 0..2047 8-float chunks
            int row = idx >> 5;
            int k0  = (idx & 31) << 3;
            const float4* p = (const float4*)(inb + row * FI + k0);
            float4 v0 = p[0], v1 = p[1];
            f16x8 h8;
            h8[0] = (f16)v0.x; h8[1] = (f16)v0.y; h8[2] = (f16)v0.z; h8[3] = (f16)v0.w;
            h8[4] = (f16)v1.x; h8[5] = (f16)v1.y; h8[6] = (f16)v1.z; h8[7] = (f16)v1.w;
            unsigned addr = (unsigned)(row * 512 + k0 * 2) ^ ((unsigned)(row & 7) << 4);
            *(f16x8*)(smem + addr) = h8;
        }
    }
    __syncthreads();

#pragma unroll 1
    for (int w = 0; w < H_; ++w) {
        // ---- GEMM1 compute: this wave's 32 cols of head w (reads sA + wfrag) ----
        f32x4 acc[4][2];
#pragma unroll
        for (int rt = 0; rt < 4; ++rt)
#pragma unroll
            for (int ct = 0; ct < 2; ++ct) {
                f32x4 z = {0.f, 0.f, 0.f, 0.f};
                acc[rt][ct] = z;
            }
#pragma unroll
        for (int kt = 0; kt < 8; ++kt) {
            f16x8 aF[4];
#pragma unroll
            for (int rt = 0; rt < 4; ++rt) {
                int row = rt * 16 + c15;
                unsigned addr = ((unsigned)(row * 512 + (kt * 32 + g * 8) * 2))
                                ^ ((unsigned)(row & 7) << 4);
                aF[rt] = *(const f16x8*)(smem + addr);
            }
            f16x8 bF[2];
#pragma unroll
            for (int ct = 0; ct < 2; ++ct) {
                int ctg = w * 16 + wv * 2 + ct;
                bF[ct] = *((const f16x8*)wfrag + ((kt * 64 + ctg) * 64 + lane));
            }
#pragma unroll
            for (int rt = 0; rt < 4; ++rt)
#pragma unroll
                for (int ct = 0; ct < 2; ++ct)
                    acc[rt][ct] = MFMA16(aF[rt], bF[ct], acc[rt][ct]);
        }

        __syncthreads();   // all waves done reading sHT (prev head's GEMM2)

        // ---- epilogue: h^T -> sHT (swizzled) + coeff partials ----
        float ciP[16], cjP[16];
#pragma unroll
        for (int q = 0; q < 16; ++q) { ciP[q] = 0.f; cjP[q] = 0.f; }
#pragma unroll
        for (int ct = 0; ct < 2; ++ct) {
            int col = wv * 32 + ct * 16 + c15;      // 0..255
            float aIc = a_i[w * FO + col];
            float aJc = a_j[w * FO + col];
#pragma unroll
            for (int rt = 0; rt < 4; ++rt) {
                f16x4 h4;
#pragma unroll
                for (int r = 0; r < 4; ++r) {
                    float v = acc[rt][ct][r];
                    ciP[rt * 4 + r] += v * aIc;
                    cjP[rt * 4 + r] += v * aJc;
                    h4[r] = (f16)v;
                }
                unsigned addr = SHT_OFF + (((unsigned)(col * 128 + (rt * 16 + g * 4) * 2))
                                           ^ ((unsigned)(col & 7) << 4));
                *(f16x4*)(smem + addr) = h4;
            }
        }
        // reduce coeff partials across the 16 lanes of each g-group
#pragma unroll
        for (int s = 1; s < 16; s <<= 1) {
#pragma unroll
            for (int q = 0; q < 16; ++q) {
                ciP[q] += __shfl_xor(ciP[q], s);
                cjP[q] += __shfl_xor(cjP[q], s);
            }
        }
        if (c15 == 0) {
#pragma unroll
            for (int q = 0; q < 16; ++q) {
                int node = (q >> 2) * 16 + g * 4 + (q & 3);
                sCi[wv * 64 + node] = ciP[q];
                sCj[wv * 64 + node] = cjP[q];
            }
        }
        __syncthreads();

        // ---- cross-wave coeff sum ----
        if (tid < 64) {
            float s = 0.f;
#pragma unroll
            for (int v = 0; v < 8; ++v) s += sCi[v * 64 + tid];
            sCiS[tid] = s;
        } else if (tid < 128) {
            int t = tid - 64;
            float s = 0.f;
#pragma unroll
            for (int v = 0; v < 8; ++v) s += sCj[v * 64 + t];
            sCjS[t] = s;
        }
        __syncthreads();

        // ---- softmax for rows rt2*16..+16 (dup'd across the 2 ch-waves) ----
        f16x8 attnF[2];
        {
            int i = rt2 * 16 + c15;
            float ci = sCiS[i];
            float sv[16];
            float m = -1e30f;
#pragma unroll
            for (int q = 0; q < 16; ++q) {
                int kt = q >> 3, jj = q & 7;
                int j = kt * 32 + g * 8 + jj;
                float e = ci + sCjS[j];
                e = fmaxf(e, 0.2f * e);          // leaky_relu slope 0.2
                float s = e * av[q];
                sv[q] = s;
                m = fmaxf(m, s);
            }
            m = fmaxf(m, __shfl_xor(m, 16));
            m = fmaxf(m, __shfl_xor(m, 32));
            float sum = 0.f;
#pragma unroll
            for (int q = 0; q < 16; ++q) { float p = __expf(sv[q] - m); sv[q] = p; sum += p; }
            sum += __shfl_xor(sum, 16);
            sum += __shfl_xor(sum, 32);
            float rs = 1.0f / sum;
#pragma unroll
            for (int q = 0; q < 16; ++q) {
                int kt = q >> 3, jj = q & 7;
                attnF[kt][jj] = (f16)(sv[q] * rs * av[q]);
            }
        }

        // ---- GEMM2: rows rt2*16..+16, cols ch*128..+128 of head w ----
        f32x4 acc2[8];
#pragma unroll
        for (int ct = 0; ct < 8; ++ct) {
            f32x4 z = {0.f, 0.f, 0.f, 0.f};
            acc2[ct] = z;
        }
#pragma unroll
        for (int kt = 0; kt < 2; ++kt) {
#pragma unroll
            for (int ct = 0; ct < 8; ++ct) {
                int col = ch * 128 + ct * 16 + c15;
                unsigned addr = SHT_OFF + (((unsigned)(col * 128 + (kt * 32 + g * 8) * 2))
                                           ^ ((unsigned)(col & 7) << 4));
                f16x8 bF = *(const f16x8*)(smem + addr);
                acc2[ct] = MFMA16(attnF[kt], bF, acc2[ct]);
            }
        }
#pragma unroll
        for (int ct = 0; ct < 8; ++ct) {
            int colg = w * FO + ch * 128 + ct * 16 + c15;
            float bv = bias[colg];
#pragma unroll
            for (int r = 0; r < 4; ++r) {
                int row = rt2 * 16 + g * 4 + r;
                out[((size_t)b * N_ + row) * HF + colg] = acc2[ct][r] + bv;
            }
        }
    }
}

extern "C" void kernel_launch(void* const* d_in, const int* in_sizes, int n_in,
                              void* d_out, int out_size, void* d_ws, size_t ws_size,
                              hipStream_t stream) {
    const float* input = (const float*)d_in[0];
    const float* adj   = (const float*)d_in[1];
    const float* W     = (const float*)d_in[2];
    const float* a_i   = (const float*)d_in[3];
    const float* a_j   = (const float*)d_in[4];
    const float* bias  = (const float*)d_in[5];
    float* outp  = (float*)d_out;
    f16*   wfrag = (f16*)d_ws;   // 512 KB

    prep_w_kernel<<<128, 256, 0, stream>>>(W, wfrag);
    gat_kernel<<<B_, 512, 0, stream>>>(input, adj, wfrag, a_i, a_j, bias, outp);
}

// Round 6
// 313.663 us; speedup vs baseline: 1.5246x; 1.1062x over previous
//
#include <hip/hip_runtime.h>

#define B_  2048
#define N_  64
#define H_  4
#define FI  256
#define FO  256
#define HF  1024   // H*F_OUT

typedef _Float16 f16;
typedef _Float16 f16x8 __attribute__((ext_vector_type(8)));
typedef _Float16 f16x4 __attribute__((ext_vector_type(4)));
typedef float f32x4 __attribute__((ext_vector_type(4)));

#define MFMA16(a,b,c) __builtin_amdgcn_mfma_f32_16x16x32_f16(a, b, c, 0, 0, 0)

// ---------------------------------------------------------------------------
// W prep: W [256][1024] f32 -> f16 MFMA B-fragments in workspace.
// layout: frag[kt(8)][ctg(64)][lane(64)][j(8)]
// element: W[kt*32 + (lane>>4)*8 + j][ctg*16 + (lane&15)]
// ---------------------------------------------------------------------------
__global__ __launch_bounds__(256) void prep_w_kernel(const float* __restrict__ W,
                                                     f16* __restrict__ wfrag) {
    int tid  = blockIdx.x * 256 + threadIdx.x;   // 0..32767
    int lane = tid & 63;
    int ctg  = (tid >> 6) & 63;
    int kt   = tid >> 12;                        // 0..7
    int krow = kt * 32 + (lane >> 4) * 8;
    int col  = ctg * 16 + (lane & 15);
    f16x8 v;
#pragma unroll
    for (int j = 0; j < 8; ++j)
        v[j] = (f16)W[(size_t)(krow + j) * HF + col];
    *((f16x8*)wfrag + tid) = v;
}

// ---------------------------------------------------------------------------
// Fused GAT kernel: 1 block = 1 batch, 8 waves, heads SEQUENTIAL.
// Per head: each wave owns a 32-col strip: GEMM1 -> h strip kept in REGISTERS
// (repacked to MFMA B-frags); attn goes through LDS (8 KB) written in
// node-PERMUTED order k' = 32n5 + 8[n3n2] + 4n4 + [n1n0] so that
// slot k'=8g+jj holds attn[i][n(g,jj)] matching the register h repack
// (rt=2*kt2+(jj>>2), r=jj&3). Softmax: wave wv owns rows 8wv..8wv+8,
// lane = (row rr = lane>>3, j-block jb = lane&7), adj held in 8 regs/lane.
// LDS (45568 B -> comfortably 2+ blocks/CU; r4/r5 evidence suggests >64KB
// blocks cannot co-reside):
//   [0, 32768)      sA    input f16 [64 row][256 k], XOR-swizzled
//   [32768, 40960)  sAttn f16 [64 i][64 k'] permuted, XOR-swizzled
//   [40960, 43008)  sCi   per-wave coeff_i partials [8][64] f32
//   [43008, 45056)  sCj   per-wave coeff_j partials [8][64] f32
//   [45056, 45312)  sCiS  summed coeff_i [64] f32
//   [45312, 45568)  sCjS  summed coeff_j [64] f32
// __launch_bounds__(512, 2): arg2 = min BLOCKS/CU on this toolchain (r3/r4
// evidence) -> VGPR cap 128.
// ---------------------------------------------------------------------------
#define SMEM_BYTES 45568
#define SATT_OFF   32768
#define SCI_OFF    40960
#define SCJ_OFF    43008
#define SCIS_OFF   45056
#define SCJS_OFF   45312

__global__ __launch_bounds__(512, 2) void gat_kernel(
    const float* __restrict__ input, const float* __restrict__ adj,
    const f16* __restrict__ wfrag, const float* __restrict__ a_i,
    const float* __restrict__ a_j, const float* __restrict__ bias,
    float* __restrict__ out)
{
    __shared__ unsigned char smem[SMEM_BYTES] __attribute__((aligned(16)));
    float* sCi  = (float*)(smem + SCI_OFF);
    float* sCj  = (float*)(smem + SCJ_OFF);
    float* sCiS = (float*)(smem + SCIS_OFF);
    float* sCjS = (float*)(smem + SCJS_OFF);

    const int b    = blockIdx.x;
    const int tid  = threadIdx.x;
    const int wv   = tid >> 6;      // wave 0..7
    const int lane = tid & 63;
    const int g    = lane >> 4;
    const int c15  = lane & 15;
    const int rr   = lane >> 3;     // softmax: row-in-wave 0..7
    const int jb   = lane & 7;      // softmax: j-block 0..7 (j = jb*8+e)

    // ---- adj for this wave's softmax rows -> 8 registers/lane ----
    float av[8];
    {
        const float* adjp = adj + (size_t)b * (N_ * N_) + (wv * 8 + rr) * N_ + jb * 8;
        float4 q0 = ((const float4*)adjp)[0];
        float4 q1 = ((const float4*)adjp)[1];
        av[0] = q0.x; av[1] = q0.y; av[2] = q0.z; av[3] = q0.w;
        av[4] = q1.x; av[5] = q1.y; av[6] = q1.z; av[7] = q1.w;
    }

    // ---- phase 0: stage input (f32->f16, swizzled) ----
    {
        const float* inb = input + (size_t)b * (N_ * FI);
#pragma unroll
        for (int c = 0; c < 4; ++c) {
            int idx = tid + 512 * c;          // 0..2047 8-float chunks
            int row = idx >> 5;
            int k0  = (idx & 31) << 3;
            const float4* p = (const float4*)(inb + row * FI + k0);
            float4 v0 = p[0], v1 = p[1];
            f16x8 h8;
            h8[0] = (f16)v0.x; h8[1] = (f16)v0.y; h8[2] = (f16)v0.z; h8[3] = (f16)v0.w;
            h8[4] = (f16)v1.x; h8[5] = (f16)v1.y; h8[6] = (f16)v1.z; h8[7] = (f16)v1.w;
            unsigned addr = (unsigned)(row * 512 + k0 * 2) ^ ((unsigned)(row & 7) << 4);
            *(f16x8*)(smem + addr) = h8;
        }
    }
    __syncthreads();

#pragma unroll 1
    for (int w = 0; w < H_; ++w) {
        // ---- P1: GEMM1, this wave's 32 cols of head w (reads sA + wfrag) ----
        f32x4 acc[4][2];
#pragma unroll
        for (int rt = 0; rt < 4; ++rt)
#pragma unroll
            for (int ct = 0; ct < 2; ++ct) {
                f32x4 z = {0.f, 0.f, 0.f, 0.f};
                acc[rt][ct] = z;
            }
#pragma unroll
        for (int kt = 0; kt < 8; ++kt) {
            f16x8 aF[4];
#pragma unroll
            for (int rt = 0; rt < 4; ++rt) {
                int row = rt * 16 + c15;
                unsigned addr = ((unsigned)(row * 512 + (kt * 32 + g * 8) * 2))
                                ^ ((unsigned)(row & 7) << 4);
                aF[rt] = *(const f16x8*)(smem + addr);
            }
            f16x8 bF[2];
#pragma unroll
            for (int ct = 0; ct < 2; ++ct) {
                int ctg = w * 16 + wv * 2 + ct;
                bF[ct] = *((const f16x8*)wfrag + ((kt * 64 + ctg) * 64 + lane));
            }
#pragma unroll
            for (int rt = 0; rt < 4; ++rt)
#pragma unroll
                for (int ct = 0; ct < 2; ++ct)
                    acc[rt][ct] = MFMA16(aF[rt], bF[ct], acc[rt][ct]);
        }

        // ---- P2: epilogue — coeff partials + repack h to B-frag registers ----
        float ciP[16], cjP[16];
#pragma unroll
        for (int q = 0; q < 16; ++q) { ciP[q] = 0.f; cjP[q] = 0.f; }
        f16x8 hB[2][2];   // [kt2][ct], elem jj = h[n=16*(2kt2+(jj>>2))+4g+(jj&3)][col]
#pragma unroll
        for (int ct = 0; ct < 2; ++ct) {
            int col = wv * 32 + ct * 16 + c15;      // 0..255 within head
            float aIc = a_i[w * FO + col];
            float aJc = a_j[w * FO + col];
#pragma unroll
            for (int rt = 0; rt < 4; ++rt) {
#pragma unroll
                for (int r = 0; r < 4; ++r) {
                    float v = acc[rt][ct][r];
                    ciP[rt * 4 + r] += v * aIc;
                    cjP[rt * 4 + r] += v * aJc;
                    // rt = 2*kt2 + bb, jj = 4*bb + r
                    hB[rt >> 1][ct][4 * (rt & 1) + r] = (f16)v;
                }
            }
        }
        // reduce coeff partials across the 16 lanes of each g-group
#pragma unroll
        for (int s = 1; s < 16; s <<= 1) {
#pragma unroll
            for (int q = 0; q < 16; ++q) {
                ciP[q] += __shfl_xor(ciP[q], s);
                cjP[q] += __shfl_xor(cjP[q], s);
            }
        }
        if (c15 == 0) {
#pragma unroll
            for (int q = 0; q < 16; ++q) {
                int node = (q >> 2) * 16 + g * 4 + (q & 3);
                sCi[wv * 64 + node] = ciP[q];
                sCj[wv * 64 + node] = cjP[q];
            }
        }
        __syncthreads();   // B1

        // ---- P3: cross-wave coeff sums ----
        if (tid < 64) {
            float s = 0.f;
#pragma unroll
            for (int v = 0; v < 8; ++v) s += sCi[v * 64 + tid];
            sCiS[tid] = s;
        } else if (tid < 128) {
            int t = tid - 64;
            float s = 0.f;
#pragma unroll
            for (int v = 0; v < 8; ++v) s += sCj[v * 64 + t];
            sCjS[t] = s;
        }
        __syncthreads();   // B2

        // ---- P4: softmax, rows 8wv..8wv+8, lane covers 8 j's of one row ----
        {
            int i = wv * 8 + rr;
            float ci = sCiS[i];
            float4 cj0 = *(const float4*)(sCjS + jb * 8);
            float4 cj1 = *(const float4*)(sCjS + jb * 8 + 4);
            float cj8[8] = {cj0.x, cj0.y, cj0.z, cj0.w, cj1.x, cj1.y, cj1.z, cj1.w};
            float sv[8];
            float m = -1e30f;
#pragma unroll
            for (int e = 0; e < 8; ++e) {
                float lr = ci + cj8[e];
                lr = fmaxf(lr, 0.2f * lr);       // leaky_relu slope 0.2
                float s = lr * av[e];
                sv[e] = s;
                m = fmaxf(m, s);
            }
            m = fmaxf(m, __shfl_xor(m, 1));
            m = fmaxf(m, __shfl_xor(m, 2));
            m = fmaxf(m, __shfl_xor(m, 4));
            float sum = 0.f;
#pragma unroll
            for (int e = 0; e < 8; ++e) { float p = __expf(sv[e] - m); sv[e] = p; sum += p; }
            sum += __shfl_xor(sum, 1);
            sum += __shfl_xor(sum, 2);
            sum += __shfl_xor(sum, 4);
            float rs = 1.0f / sum;
            // write attn in permuted k' order: two 8B chunks
            f16x4 lo, hi;
#pragma unroll
            for (int e = 0; e < 4; ++e) lo[e] = (f16)(sv[e] * rs * av[e]);
#pragma unroll
            for (int e = 0; e < 4; ++e) hi[e] = (f16)(sv[4 + e] * rs * av[4 + e]);
            unsigned kbase = (unsigned)(32 * (jb >> 2) + 16 * (jb & 1) + 4 * ((jb >> 1) & 1));
            unsigned a0 = SATT_OFF + (((unsigned)(i * 128) + kbase * 2) ^ ((unsigned)(i & 7) << 4));
            unsigned a1 = SATT_OFF + (((unsigned)(i * 128) + (kbase + 8) * 2) ^ ((unsigned)(i & 7) << 4));
            *(f16x4*)(smem + a0) = lo;
            *(f16x4*)(smem + a1) = hi;
        }
        __syncthreads();   // B3

        // ---- P5: GEMM2 — out rows x this wave's 32 cols; B = h from regs ----
#pragma unroll
        for (int it = 0; it < 4; ++it) {
            f32x4 acc2[2];
#pragma unroll
            for (int ct = 0; ct < 2; ++ct) {
                f32x4 z = {0.f, 0.f, 0.f, 0.f};
                acc2[ct] = z;
            }
#pragma unroll
            for (int kt2 = 0; kt2 < 2; ++kt2) {
                int i = it * 16 + c15;
                unsigned addr = SATT_OFF + (((unsigned)(i * 128 + (kt2 * 32 + g * 8) * 2))
                                            ^ ((unsigned)(i & 7) << 4));
                f16x8 aF = *(const f16x8*)(smem + addr);
#pragma unroll
                for (int ct = 0; ct < 2; ++ct)
                    acc2[ct] = MFMA16(aF, hB[kt2][ct], acc2[ct]);
            }
#pragma unroll
            for (int ct = 0; ct < 2; ++ct) {
                int colg = w * FO + wv * 32 + ct * 16 + c15;
                float bv = bias[colg];
#pragma unroll
                for (int r = 0; r < 4; ++r) {
                    int row = it * 16 + g * 4 + r;
                    out[((size_t)b * N_ + row) * HF + colg] = acc2[ct][r] + bv;
                }
            }
        }
    }
}

extern "C" void kernel_launch(void* const* d_in, const int* in_sizes, int n_in,
                              void* d_out, int out_size, void* d_ws, size_t ws_size,
                              hipStream_t stream) {
    const float* input = (const float*)d_in[0];
    const float* adj   = (const float*)d_in[1];
    const float* W     = (const float*)d_in[2];
    const float* a_i   = (const float*)d_in[3];
    const float* a_j   = (const float*)d_in[4];
    const float* bias  = (const float*)d_in[5];
    float* outp  = (float*)d_out;
    f16*   wfrag = (f16*)d_ws;   // 512 KB

    prep_w_kernel<<<128, 256, 0, stream>>>(W, wfrag);
    gat_kernel<<<B_, 512, 0, stream>>>(input, adj, wfrag, a_i, a_j, bias, outp);
}

// Round 7
// 262.546 us; speedup vs baseline: 1.8214x; 1.1947x over previous
//
#include <hip/hip_runtime.h>

#define B_  2048
#define N_  64
#define H_  4
#define FI  256
#define FO  256
#define HF  1024   // H*F_OUT

typedef _Float16 f16;
typedef _Float16 f16x8 __attribute__((ext_vector_type(8)));
typedef _Float16 f16x4 __attribute__((ext_vector_type(4)));
typedef float f32x4 __attribute__((ext_vector_type(4)));

#define MFMA16(a,b,c) __builtin_amdgcn_mfma_f32_16x16x32_f16(a, b, c, 0, 0, 0)

// ---------------------------------------------------------------------------
// W prep: W [256][1024] f32 -> f16 MFMA B-fragments in workspace.
// layout: frag[kt(8)][ctg(64)][lane(64)][j(8)]
// element: W[kt*32 + (lane>>4)*8 + j][ctg*16 + (lane&15)]
// ---------------------------------------------------------------------------
__global__ __launch_bounds__(256) void prep_w_kernel(const float* __restrict__ W,
                                                     f16* __restrict__ wfrag) {
    int tid  = blockIdx.x * 256 + threadIdx.x;   // 0..32767
    int lane = tid & 63;
    int ctg  = (tid >> 6) & 63;
    int kt   = tid >> 12;                        // 0..7
    int krow = kt * 32 + (lane >> 4) * 8;
    int col  = ctg * 16 + (lane & 15);
    f16x8 v;
#pragma unroll
    for (int j = 0; j < 8; ++j)
        v[j] = (f16)W[(size_t)(krow + j) * HF + col];
    *((f16x8*)wfrag + tid) = v;
}

// ---------------------------------------------------------------------------
// Fused GAT: 1 block = 1 batch, 1024 threads = 16 waves = (head w, quarter ch2).
// 3 barriers TOTAL per block (r4-r6's per-head barrier loop removed).
// Wave (w,ch2) owns 64 cols of head w:
//   GEMM1 (2 chunks of 2 col-tiles) -> h strip in REGISTERS as B-frags hB,
//   coeff partials -> LDS -> B1 -> cross-wave sum -> B2 ->
//   softmax per row-tile fully in-register in PERMUTED A-frag layout
//   (k' slot = 32*n5 + 8*[n3n2] + 4*n4 + [n1n0]; duplicated across the 4
//   waves of a head), GEMM2 with all-register operands, store.
// adj staged once as f16 in the same permuted k' layout (8 KB, swizzled).
// LDS (51200 B):
//   [0, 32768)      sA     input f16 [64 row][256 k], XOR-swizzled
//   [32768, 40960)  sAdjP  adj f16 [64 i][64 k'] permuted, XOR-swizzled
//   [40960, 45056)  sCi    per-wave coeff_i partials [16][64] f32
//   [45056, 49152)  sCj    per-wave coeff_j partials [16][64] f32
//   [49152, 50176)  sCiS   summed coeff_i [4 head][64] f32
//   [50176, 51200)  sCjS   summed coeff_j [4 head][64] f32
// __launch_bounds__(1024,1): VGPR cap 128 (4 waves/SIMD), no co-residency
// needed — the 16 waves of one block fill the CU to the VGPR-allowed max.
// ---------------------------------------------------------------------------
#define SMEM_BYTES 51200
#define SADJ_OFF   32768
#define SCI_OFF    40960
#define SCJ_OFF    45056
#define SCIS_OFF   49152
#define SCJS_OFF   50176

__global__ __launch_bounds__(1024, 1) void gat_kernel(
    const float* __restrict__ input, const float* __restrict__ adj,
    const f16* __restrict__ wfrag, const float* __restrict__ a_i,
    const float* __restrict__ a_j, const float* __restrict__ bias,
    float* __restrict__ out)
{
    __shared__ unsigned char smem[SMEM_BYTES] __attribute__((aligned(16)));
    float* sCi  = (float*)(smem + SCI_OFF);
    float* sCj  = (float*)(smem + SCJ_OFF);
    float* sCiS = (float*)(smem + SCIS_OFF);
    float* sCjS = (float*)(smem + SCJS_OFF);

    const int b    = blockIdx.x;
    const int tid  = threadIdx.x;
    const int wv   = tid >> 6;      // wave 0..15
    const int w    = wv >> 2;       // head 0..3
    const int ch2  = wv & 3;        // col-quarter 0..3
    const int lane = tid & 63;
    const int g    = lane >> 4;
    const int c15  = lane & 15;

    // ---- phase 0: stage input (f32->f16, swizzled) + adj (f16, permuted) ----
    {
        const float* inb = input + (size_t)b * (N_ * FI);
#pragma unroll
        for (int c = 0; c < 2; ++c) {
            int idx = tid + 1024 * c;         // 0..2047 8-float chunks
            int row = idx >> 5;
            int k0  = (idx & 31) << 3;
            const float4* p = (const float4*)(inb + row * FI + k0);
            float4 v0 = p[0], v1 = p[1];
            f16x8 h8;
            h8[0] = (f16)v0.x; h8[1] = (f16)v0.y; h8[2] = (f16)v0.z; h8[3] = (f16)v0.w;
            h8[4] = (f16)v1.x; h8[5] = (f16)v1.y; h8[6] = (f16)v1.z; h8[7] = (f16)v1.w;
            unsigned addr = (unsigned)(row * 512 + k0 * 2) ^ ((unsigned)(row & 7) << 4);
            *(f16x8*)(smem + addr) = h8;
        }
        if (tid < 512) {
            int i  = tid >> 3;
            int jb = tid & 7;                 // node block n = 8*jb + e
            const float* ap = adj + (size_t)b * (N_ * N_) + i * N_ + jb * 8;
            float4 q0 = ((const float4*)ap)[0];
            float4 q1 = ((const float4*)ap)[1];
            // permuted slot: n = 8jb+e -> k' = 32*(jb>>2) + 8*gg + 4*((jb>>1)&1) + (e&3)
            // e=0..3 -> gg = 2*(jb&1); e=4..7 -> gg = 2*(jb&1)+1
            f16x4 lo, hi;
            lo[0] = (f16)q0.x; lo[1] = (f16)q0.y; lo[2] = (f16)q0.z; lo[3] = (f16)q0.w;
            hi[0] = (f16)q1.x; hi[1] = (f16)q1.y; hi[2] = (f16)q1.z; hi[3] = (f16)q1.w;
            unsigned k0p = (unsigned)(32 * (jb >> 2) + 16 * (jb & 1) + 4 * ((jb >> 1) & 1));
            unsigned sw  = (unsigned)(i & 7) << 4;
            *(f16x4*)(smem + SADJ_OFF + (((unsigned)(i * 128) + k0p * 2) ^ sw)) = lo;
            *(f16x4*)(smem + SADJ_OFF + (((unsigned)(i * 128) + (k0p + 8) * 2) ^ sw)) = hi;
        }
    }
    __syncthreads();

    // ---- GEMM1: this wave's 64 cols of head w; h kept in registers ----
    float ciP[16], cjP[16];
#pragma unroll
    for (int q = 0; q < 16; ++q) { ciP[q] = 0.f; cjP[q] = 0.f; }
    f16x8 hB[2][4];   // [kt2][ct] B-frags: slot jj = h[16*(2kt2+(jj>>2))+4g+(jj&3)][col]

#pragma unroll
    for (int cc = 0; cc < 2; ++cc) {
        f32x4 acc[4][2];
#pragma unroll
        for (int rt = 0; rt < 4; ++rt)
#pragma unroll
            for (int ctl = 0; ctl < 2; ++ctl) {
                f32x4 z = {0.f, 0.f, 0.f, 0.f};
                acc[rt][ctl] = z;
            }
#pragma unroll
        for (int kt = 0; kt < 8; ++kt) {
            f16x8 aF[4];
#pragma unroll
            for (int rt = 0; rt < 4; ++rt) {
                int row = rt * 16 + c15;
                unsigned addr = ((unsigned)(row * 512 + (kt * 32 + g * 8) * 2))
                                ^ ((unsigned)(row & 7) << 4);
                aF[rt] = *(const f16x8*)(smem + addr);
            }
            f16x8 bF[2];
#pragma unroll
            for (int ctl = 0; ctl < 2; ++ctl) {
                int ctg = w * 16 + ch2 * 4 + cc * 2 + ctl;
                bF[ctl] = *((const f16x8*)wfrag + ((kt * 64 + ctg) * 64 + lane));
            }
#pragma unroll
            for (int rt = 0; rt < 4; ++rt)
#pragma unroll
                for (int ctl = 0; ctl < 2; ++ctl)
                    acc[rt][ctl] = MFMA16(aF[rt], bF[ctl], acc[rt][ctl]);
        }
        // epilogue: coeff partials + pack h into B-frag registers
#pragma unroll
        for (int ctl = 0; ctl < 2; ++ctl) {
            int ct = cc * 2 + ctl;
            int colg = w * FO + ch2 * 64 + ct * 16 + c15;
            float aIc = a_i[colg];
            float aJc = a_j[colg];
#pragma unroll
            for (int rt = 0; rt < 4; ++rt) {
#pragma unroll
                for (int r = 0; r < 4; ++r) {
                    float v = acc[rt][ctl][r];
                    ciP[rt * 4 + r] += v * aIc;
                    cjP[rt * 4 + r] += v * aJc;
                    hB[rt >> 1][ct][4 * (rt & 1) + r] = (f16)v;
                }
            }
        }
    }

    // ---- coeff reduce over the 16 c15-lanes of each g-group ----
#pragma unroll
    for (int s = 1; s < 16; s <<= 1) {
#pragma unroll
        for (int q = 0; q < 16; ++q) {
            ciP[q] += __shfl_xor(ciP[q], s);
            cjP[q] += __shfl_xor(cjP[q], s);
        }
    }
    if (c15 == 0) {
#pragma unroll
        for (int q = 0; q < 16; ++q) {
            int node = (q >> 2) * 16 + g * 4 + (q & 3);
            sCi[wv * 64 + node] = ciP[q];
            sCj[wv * 64 + node] = cjP[q];
        }
    }
    __syncthreads();   // B1

    // ---- cross-wave coeff sums (per head) ----
    if (tid < 512) {
        int wq    = tid >> 7;        // head
        int which = (tid >> 6) & 1;
        int node  = tid & 63;
        const float* src = (which == 0 ? sCi : sCj) + (wq * 4) * 64 + node;
        float s = src[0] + src[64] + src[128] + src[192];
        (which == 0 ? sCiS : sCjS)[wq * 64 + node] = s;
    }
    __syncthreads();   // B2

    // ---- per row-tile: in-register softmax (permuted layout) + GEMM2 ----
#pragma unroll 1
    for (int it = 0; it < 4; ++it) {
        int i = it * 16 + c15;
        float ci = sCiS[w * 64 + i];
        // adj (permuted k' layout) : two b128 reads
        unsigned sw = (unsigned)(i & 7) << 4;
        f16x8 adjv0 = *(const f16x8*)(smem + SADJ_OFF + (((unsigned)(i * 128) + (g * 8) * 2) ^ sw));
        f16x8 adjv1 = *(const f16x8*)(smem + SADJ_OFF + (((unsigned)(i * 128) + (32 + g * 8) * 2) ^ sw));
        // coeff_j for this lane's 16 nodes: n = 16t + 4g + r
        float cj[16];
#pragma unroll
        for (int t = 0; t < 4; ++t) {
            float4 c4 = *(const float4*)(sCjS + w * 64 + t * 16 + 4 * g);
            cj[t * 4 + 0] = c4.x; cj[t * 4 + 1] = c4.y;
            cj[t * 4 + 2] = c4.z; cj[t * 4 + 3] = c4.w;
        }
        float sv[16], av[16];
#pragma unroll
        for (int q = 0; q < 16; ++q)
            av[q] = (float)(q < 8 ? adjv0[q & 7] : adjv1[q & 7]);
        float m = -1e30f;
#pragma unroll
        for (int q = 0; q < 16; ++q) {
            float e = ci + cj[q];
            e = fmaxf(e, 0.2f * e);          // leaky_relu slope 0.2
            float s = e * av[q];
            sv[q] = s;
            m = fmaxf(m, s);
        }
        m = fmaxf(m, __shfl_xor(m, 16));
        m = fmaxf(m, __shfl_xor(m, 32));
        float sum = 0.f;
#pragma unroll
        for (int q = 0; q < 16; ++q) { float p = __expf(sv[q] - m); sv[q] = p; sum += p; }
        sum += __shfl_xor(sum, 16);
        sum += __shfl_xor(sum, 32);
        float rs = 1.0f / sum;
        f16x8 atF[2];
#pragma unroll
        for (int jj = 0; jj < 8; ++jj) {
            atF[0][jj] = (f16)(sv[jj] * rs * av[jj]);
            atF[1][jj] = (f16)(sv[8 + jj] * rs * av[8 + jj]);
        }
        // GEMM2: all-register MFMA
        f32x4 acc2[4];
#pragma unroll
        for (int ct = 0; ct < 4; ++ct) {
            f32x4 z = {0.f, 0.f, 0.f, 0.f};
            acc2[ct] = z;
        }
#pragma unroll
        for (int kt2 = 0; kt2 < 2; ++kt2)
#pragma unroll
            for (int ct = 0; ct < 4; ++ct)
                acc2[ct] = MFMA16(atF[kt2], hB[kt2][ct], acc2[ct]);
#pragma unroll
        for (int ct = 0; ct < 4; ++ct) {
            int colg = w * FO + ch2 * 64 + ct * 16 + c15;
            float bv = bias[colg];
#pragma unroll
            for (int r = 0; r < 4; ++r) {
                int row = it * 16 + g * 4 + r;
                out[((size_t)b * N_ + row) * HF + colg] = acc2[ct][r] + bv;
            }
        }
    }
}

extern "C" void kernel_launch(void* const* d_in, const int* in_sizes, int n_in,
                              void* d_out, int out_size, void* d_ws, size_t ws_size,
                              hipStream_t stream) {
    const float* input = (const float*)d_in[0];
    const float* adj   = (const float*)d_in[1];
    const float* W     = (const float*)d_in[2];
    const float* a_i   = (const float*)d_in[3];
    const float* a_j   = (const float*)d_in[4];
    const float* bias  = (const float*)d_in[5];
    float* outp  = (float*)d_out;
    f16*   wfrag = (f16*)d_ws;   // 512 KB

    prep_w_kernel<<<128, 256, 0, stream>>>(W, wfrag);
    gat_kernel<<<B_, 1024, 0, stream>>>(input, adj, wfrag, a_i, a_j, bias, outp);
}